// Round 4
// baseline (99.294 us; speedup 1.0000x reference)
//
#include <hip/hip_runtime.h>

#define N_KPS 1024
#define N_PTS 120000
#define BLOCK 512                  // 8 waves per block
#define KSPLIT 8                   // one wave per K-chunk
#define KCHUNK (N_KPS / KSPLIT)    // 128 control points per wave
#define PTS_PER_THREAD 4
#define PTS_PER_BLOCK 256          // 64 lanes x 4 points/thread
#define CHUNK 8                    // ctrl points per chunk
#define NCHUNK (KCHUNK / CHUNK)    // 16

typedef float v2f __attribute__((ext_vector_type(2)));
typedef unsigned int v2u __attribute__((ext_vector_type(2)));

// r6: full unroll + fma-folded epsilon: 82.4 -> 78.3. r7: 4 pts/thread: FLAT
// (78.9) — zero per-interaction op change => exec-bound, not latency-bound.
// Model fit across r5/r6/r7 (kernel ~= dur - 40.3us harness fill):
//   T_SIMD = waves/SIMD * (2*N_VALU + T_log*N_log)  fits all three rounds at
//   T_log ~= 35 cyc per wave64 v_log_f32, SERIALIZED with VALU (no overlap).
//   => logs are ~55% of kernel time (512 x 35 of 25.1k cyc/wave in r7).
// r8 (this round): replace v_log_f32 with a VALU-only log2:
//   x = 2^E * m, m in [1,2): E via bits>>23 (d2 >= 1e-37 => always normal,
//   sign 0). log2(m) via deg-6 poly in u = 2m-3 in [-1,1], coefficients from
//   the closed-form Chebyshev expansion of ln(3+u) (rho = 3-2sqrt2), checked
//   at u=-1/0/+1 (resid <= 7e-6). -127-1 folded into c0. 11 VALU = 22 cyc
//   vs 35 => per-wave 25.1k -> 18.4k cyc.
// Prediction: kernel 38 -> ~28us, dur 78.9 -> 67-70; absmax +<=0.05.
// Flat => serialized-trans model wrong, revert.
static __device__ __forceinline__ v2f flog2(v2f x) {
    v2u bits = __builtin_bit_cast(v2u, x);
    v2u E = bits >> 23;                       // biased exponent (sign==0)
    v2f ef = __builtin_convertvector(E, v2f); // v_cvt_f32_u32
    v2u mb = (bits & 0x007FFFFFu) | 0x3F800000u;
    v2f m = __builtin_bit_cast(v2f, mb);      // m in [1,2)
    v2f u = __builtin_elementwise_fma(m, v2f{2.f, 2.f}, v2f{-3.f, -3.f});
    // P(u) = log2(m) - 128  (deg-6, Chebyshev-derived; P(-1)=-127, P(1)=-126)
    v2f p = v2f{-0.00039257f, -0.00039257f};
    p = __builtin_elementwise_fma(p, u, v2f{ 0.00137278f,  0.00137278f});
    p = __builtin_elementwise_fma(p, u, v2f{-0.00441182f, -0.00441182f});
    p = __builtin_elementwise_fma(p, u, v2f{ 0.01771476f,  0.01771476f});
    p = __builtin_elementwise_fma(p, u, v2f{-0.08015808f, -0.08015808f});
    p = __builtin_elementwise_fma(p, u, v2f{ 0.48091063f,  0.48091063f});
    p = __builtin_elementwise_fma(p, u, v2f{-126.41504303f, -126.41504303f});
    return ef + p;                            // log2(x)
}

__global__ __launch_bounds__(BLOCK) void tps_warp_kernel(
    const float2* __restrict__ pts,
    const float*  __restrict__ kps,
    const float*  __restrict__ W,
    float2*       __restrict__ out)
{
    // part[set][wv][lane]: set 0 = points {0,1}, set 1 = points {2,3}.
    __shared__ float4 part[2][KSPLIT][64];

    const int lane = threadIdx.x & 63;
    // Provably wave-uniform wave id -> SGPR -> scalar loads for kps/W.
    const int wv = __builtin_amdgcn_readfirstlane(threadIdx.x) >> 6;

    const int base = blockIdx.x * PTS_PER_BLOCK;
    const int j0 = base + 0 * 64 + lane;
    const int j1 = base + 1 * 64 + lane;
    const int j2 = base + 2 * 64 + lane;
    const int j3 = base + 3 * 64 + lane;
    const float2 p0 = pts[j0 < N_PTS ? j0 : N_PTS - 1];
    const float2 p1 = pts[j1 < N_PTS ? j1 : N_PTS - 1];
    const float2 p2 = pts[j2 < N_PTS ? j2 : N_PTS - 1];
    const float2 p3 = pts[j3 < N_PTS ? j3 : N_PTS - 1];

    v2f pxA = {p0.x, p1.x}, pyA = {p0.y, p1.y};
    v2f pxB = {p2.x, p3.x}, pyB = {p2.y, p3.y};
    v2f zxA = {0.f, 0.f}, zyA = {0.f, 0.f};
    v2f zxB = {0.f, 0.f}, zyB = {0.f, 0.f};
    const v2f tiny = {1e-37f, 1e-37f};

    auto eval = [&](float kx, float ky, float wx, float wy) {
        const v2f kxx = {kx, kx}, kyy = {ky, ky};
        const v2f wxx = {wx, wx}, wyy = {wy, wy};
        v2f dxA = kxx - pxA, dyA = kyy - pyA;
        v2f dxB = kxx - pxB, dyB = kyy - pyB;
        // d2 >= 1e-37 always (epsilon in chain): positive + normal, so the
        // bit-trick log2 is safe; d2==0 case -> 1e-37*log2(1e-37) ~ 0 matches
        // reference where(l2==0,1)->0.
        v2f d2A = __builtin_elementwise_fma(
            dyA, dyA, __builtin_elementwise_fma(dxA, dxA, tiny));
        v2f d2B = __builtin_elementwise_fma(
            dyB, dyB, __builtin_elementwise_fma(dxB, dxB, tiny));
        v2f tA = flog2(d2A);
        v2f tB = flog2(d2B);
        v2f vA = d2A * tA;                   // 0.5*ln2 folded in at the end
        v2f vB = d2B * tB;
        zxA = __builtin_elementwise_fma(vA, wxx, zxA);
        zyA = __builtin_elementwise_fma(vA, wyy, zyA);
        zxB = __builtin_elementwise_fma(vB, wxx, zxB);
        zyB = __builtin_elementwise_fma(vB, wyy, zyB);
    };

    // float4 view of ctrl data: kp4[t] = {k[2t].x,k[2t].y,k[2t+1].x,k[2t+1].y}.
    const float4* __restrict__ kp4 = (const float4*)kps;   // 512 entries
    const float4* __restrict__ wp4 = (const float4*)W;
    const int cbase = wv * (KCHUNK / 2);                   // float4 index base

    #pragma unroll
    for (int c = 0; c < NCHUNK; ++c) {
        float4 kc[4], wc[4];
        #pragma unroll
        for (int t = 0; t < 4; ++t) {
            kc[t] = kp4[cbase + c * 4 + t];
            wc[t] = wp4[cbase + c * 4 + t];
        }
        #pragma unroll
        for (int t = 0; t < 4; ++t) {
            eval(kc[t].x, kc[t].y, wc[t].x, wc[t].y);
            eval(kc[t].z, kc[t].w, wc[t].z, wc[t].w);
        }
    }

    part[0][wv][lane] = make_float4(zxA.x, zyA.x, zxA.y, zyA.y);
    part[1][wv][lane] = make_float4(zxB.x, zyB.x, zxB.y, zyB.y);
    __syncthreads();

    // Tail: waves 0..3 each finalize one point set; compile-time indices only.
    if (wv < 4) {
        const bool hiHalf = (wv & 1);        // pick .z/.w vs .x/.y
        const int setB = (wv >> 1);          // pick part[1] vs part[0]
        const float2 p = (wv == 0) ? p0 : (wv == 1) ? p1 : (wv == 2) ? p2 : p3;
        const int j   = (wv == 0) ? j0 : (wv == 1) ? j1 : (wv == 2) ? j2 : j3;

        float sx = 0.f, sy = 0.f;
        #pragma unroll
        for (int w = 0; w < KSPLIT; ++w) {
            float4 a = part[setB][w][lane];
            sx += hiHalf ? a.z : a.x;
            sy += hiHalf ? a.w : a.y;
        }

        const float scale = 0.34657359027997264f;  // 0.5 * ln(2)
        float w1x = W[2048], w1y = W[2049];
        float wxx = W[2050], wxy = W[2051];
        float wyx = W[2052], wyy = W[2053];

        if (j < N_PTS) {
            float ox = p.x + fmaf(scale, sx, fmaf(wxx, p.x, fmaf(wyx, p.y, w1x)));
            float oy = p.y + fmaf(scale, sy, fmaf(wxy, p.x, fmaf(wyy, p.y, w1y)));
            out[j] = make_float2(ox, oy);
        }
    }
}

extern "C" void kernel_launch(void* const* d_in, const int* in_sizes, int n_in,
                              void* d_out, int out_size, void* d_ws, size_t ws_size,
                              hipStream_t stream) {
    const float* pts = (const float*)d_in[0];   // [120000, 2]
    const float* kps = (const float*)d_in[1];   // [1024, 2]
    const float* W   = (const float*)d_in[2];   // [1027, 2]
    float* out = (float*)d_out;                 // [120000, 2]

    const int grid = (N_PTS + PTS_PER_BLOCK - 1) / PTS_PER_BLOCK;  // 469
    tps_warp_kernel<<<grid, BLOCK, 0, stream>>>(
        (const float2*)pts, kps, W, (float2*)out);
}

// Round 6
// 88.325 us; speedup vs baseline: 1.1242x; 1.1242x over previous
//
#include <hip/hip_runtime.h>

#define N_KPS 1024
#define N_PTS 120000
#define BLOCK 512                  // 8 waves per block
#define KSPLIT 8                   // one wave per ctrl chunk
#define KCHUNK (N_KPS / KSPLIT)    // 128 ctrl points per wave
#define PTS_PER_LANE 3
#define PTS_PER_BLOCK 192          // 64 lanes x 3 pts -> 625 blocks EXACT

typedef float v4f __attribute__((ext_vector_type(4)));

// r8: poly-log regression proved kernel is VALU-issue-bound; VALUBusy 66.8%
//     with 33% idle and NO trans work => s_load bursts (80 SGPR ~1.5-chunk
//     lookahead, ~300cyc L2 waits, 3.66 w/SIMD) are the idle source.
// r9: LDS-SoA broadcast + inline-asm v_pk_*_f32: FAILED absmax 4e8. Audit
//     found no indexing/race bug; the unverifiable element is the VOP3P asm
//     (op_sel defaults / 64-bit operand printing). Indicted, not convicted.
// r10 (this round): ISOLATE. Keep the structural medicine, drop the asm:
//   - ctrl data staged to LDS as AoS v4f {kx,ky,wx,wy}: ONE uniform-address
//     ds_read_b128 (HW broadcast, conflict-free, ~4cyc) per ctrl point.
//     No s_loads in the hot loop, no SGPR pressure, unroll-8 scheduling.
//   - math byte-identical to verified r6: dx/dy subtract form, fma-folded
//     1e-37 (log arg always positive/normal; d2==0 -> ~0 contribution),
//     real v_log_f32 on the trans pipe, 0.5*ln2 folded into epilogue.
//   - 3 pts/lane, 192 pts/block, 625 blocks exact (zero bounds checks),
//     8 waves/block, KSPLIT=8 -> 5000 waves = 4.9/SIMD.
//   - tail: compile-time-indexed selects only (no runtime-indexed arrays).
// Arithmetic: VALU 122.9M x 7 ops = 10.9us; trans ~9us (overlaps); LDS
// broadcast ~0.5us. Predict kernel ~14-18us, dur -> 58-64, VALUBusy 55-70%,
// LDS_BANK_CONFLICT ~0. Fail => r9 structure was the bug; >=70us => remodel.
__global__ __launch_bounds__(BLOCK) void tps_warp_kernel(
    const float2* __restrict__ pts,
    const float*  __restrict__ kps,
    const float*  __restrict__ W,
    float2*       __restrict__ out)
{
    __shared__ v4f ctrl[N_KPS];                        // 16 KB AoS tile
    __shared__ float2 part[PTS_PER_LANE][KSPLIT][64];  // 12 KB partials

    const int tid = threadIdx.x;
    const int lane = tid & 63;
    // Provably wave-uniform wave id -> SGPR.
    const int wv = __builtin_amdgcn_readfirstlane(tid) >> 6;

    // Stage kps/W -> LDS AoS. Coalesced float2 global loads, stride-1
    // ds_write_b128 (16B/lane, conflict-free). 2 iterations.
    {
        const float2* kp2 = (const float2*)kps;
        const float2* wp2 = (const float2*)W;
        #pragma unroll
        for (int i = tid; i < N_KPS; i += BLOCK) {
            float2 k = kp2[i];
            float2 w = wp2[i];
            ctrl[i] = v4f{k.x, k.y, w.x, w.y};
        }
    }

    const int base = blockIdx.x * PTS_PER_BLOCK;       // 625*192 = 120000
    float px0, py0, px1, py1, px2, py2;
    {
        float2 p0 = pts[base + 0 * 64 + lane];
        float2 p1 = pts[base + 1 * 64 + lane];
        float2 p2 = pts[base + 2 * 64 + lane];
        px0 = p0.x; py0 = p0.y;
        px1 = p1.x; py1 = p1.y;
        px2 = p2.x; py2 = p2.y;
    }

    __syncthreads();

    float ax0 = 0.f, ay0 = 0.f;
    float ax1 = 0.f, ay1 = 0.f;
    float ax2 = 0.f, ay2 = 0.f;

    const int c0 = wv * KCHUNK;
    #pragma unroll 8
    for (int i = 0; i < KCHUNK; ++i) {
        // Lane-uniform address -> ds_read_b128 broadcast, conflict-free.
        v4f c = ctrl[c0 + i];
        const float kx = c.x, ky = c.y, wx = c.z, wy = c.w;
        {
            float dx = kx - px0, dy = ky - py0;
            float d2 = fmaf(dy, dy, fmaf(dx, dx, 1e-37f));
            float v = d2 * __log2f(d2);
            ax0 = fmaf(v, wx, ax0);
            ay0 = fmaf(v, wy, ay0);
        }
        {
            float dx = kx - px1, dy = ky - py1;
            float d2 = fmaf(dy, dy, fmaf(dx, dx, 1e-37f));
            float v = d2 * __log2f(d2);
            ax1 = fmaf(v, wx, ax1);
            ay1 = fmaf(v, wy, ay1);
        }
        {
            float dx = kx - px2, dy = ky - py2;
            float d2 = fmaf(dy, dy, fmaf(dx, dx, 1e-37f));
            float v = d2 * __log2f(d2);
            ax2 = fmaf(v, wx, ax2);
            ay2 = fmaf(v, wy, ay2);
        }
    }

    part[0][wv][lane] = make_float2(ax0, ay0);
    part[1][wv][lane] = make_float2(ax1, ay1);
    part[2][wv][lane] = make_float2(ax2, ay2);
    __syncthreads();

    // Waves 0..2 each finalize one point set; compile-time selects only.
    if (wv < PTS_PER_LANE) {
        const int s = wv;
        float sx = 0.f, sy = 0.f;
        #pragma unroll
        for (int w = 0; w < KSPLIT; ++w) {
            float2 a = part[s][w][lane];   // s is wave-uniform (SGPR index)
            sx += a.x;
            sy += a.y;
        }

        const float qx = (s == 0) ? px0 : (s == 1) ? px1 : px2;
        const float qy = (s == 0) ? py0 : (s == 1) ? py1 : py2;

        const float scale = 0.34657359027997264f;  // 0.5 * ln(2)
        float w1x = W[2048], w1y = W[2049];
        float wxx = W[2050], wxy = W[2051];
        float wyx = W[2052], wyy = W[2053];

        float ox = qx + fmaf(scale, sx, fmaf(wxx, qx, fmaf(wyx, qy, w1x)));
        float oy = qy + fmaf(scale, sy, fmaf(wxy, qx, fmaf(wyy, qy, w1y)));
        out[base + s * 64 + lane] = make_float2(ox, oy);
    }
}

extern "C" void kernel_launch(void* const* d_in, const int* in_sizes, int n_in,
                              void* d_out, int out_size, void* d_ws, size_t ws_size,
                              hipStream_t stream) {
    const float* pts = (const float*)d_in[0];   // [120000, 2]
    const float* kps = (const float*)d_in[1];   // [1024, 2]
    const float* W   = (const float*)d_in[2];   // [1027, 2]
    float* out = (float*)d_out;                 // [120000, 2]

    const int grid = N_PTS / PTS_PER_BLOCK;     // 625 exact
    tps_warp_kernel<<<grid, BLOCK, 0, stream>>>(
        (const float2*)pts, kps, W, (float2*)out);
}